// Round 1
// baseline (243.169 us; speedup 1.0000x reference)
//
#include <hip/hip_runtime.h>
#include <cstdint>
#include <type_traits>

// Problem: GPT MHA forward. B=2, T=2048, C=1024, H=16, d=64.
// Pipeline (all on `stream`):
//   1. cast x (fp32 -> bf16)                      [4096 x 1024]
//   2. transpose+cast wq,wk,wv,wo -> bf16 W^T     [4 x 1024 x 1024]
//   3. concat biases bq|bk|bv                     [3072]
//   4. GEMM: QKV = xb @ [wq|wk|wv] + bias         [4096 x 3072] bf16
//   5. causal flash attention -> Obuf             [4096 x 1024] bf16
//   6. GEMM: out = Obuf @ wo + bo                 [4096 x 1024] fp32
//
// Workspace layout (needs ~48.1 MB):
//   0        xb      8 MB
//   8 MB     wqkvT   6 MB   (w^T, bf16, rows n, cols k)
//   14 MB    woT     2 MB
//   16 MB    QKV    24 MB
//   40 MB    Obuf    8 MB
//   48 MB    biasqkv 12 KB

#define TSEQ  2048
#define BATCH 2
#define CDIM  1024
#define NHEAD 16
#define DHEAD 64
#define NROWS (BATCH * TSEQ)  // 4096

typedef unsigned short u16;
typedef u16   u16x8  __attribute__((ext_vector_type(8)));
typedef __bf16 bf16x8 __attribute__((ext_vector_type(8)));
typedef float f32x4  __attribute__((ext_vector_type(4)));

__device__ __forceinline__ u16 f2bf(float f) {
  union { float f; uint32_t u; } v; v.f = f;
  uint32_t u = v.u;
  return (u16)((u + 0x7FFFu + ((u >> 16) & 1u)) >> 16);  // RNE
}

__device__ __forceinline__ f32x4 mfma_bf16(u16x8 a, u16x8 b, f32x4 c) {
  return __builtin_amdgcn_mfma_f32_16x16x32_bf16(
      __builtin_bit_cast(bf16x8, a), __builtin_bit_cast(bf16x8, b), c, 0, 0, 0);
}

// ---------------- prep kernels ----------------

__global__ __launch_bounds__(256) void cast_x_kernel(const float* __restrict__ in,
                                                     u16* __restrict__ out, int n4) {
  int i = blockIdx.x * 256 + threadIdx.x;
  if (i < n4) {
    float4 v = ((const float4*)in)[i];
    uint32_t lo = (uint32_t)f2bf(v.x) | ((uint32_t)f2bf(v.y) << 16);
    uint32_t hi = (uint32_t)f2bf(v.z) | ((uint32_t)f2bf(v.w) << 16);
    ((uint2*)out)[i] = make_uint2(lo, hi);
  }
}

__global__ __launch_bounds__(256) void transpose_cast_kernel(
    const float* __restrict__ w0, const float* __restrict__ w1,
    const float* __restrict__ w2, const float* __restrict__ w3,
    u16* __restrict__ outQKV, u16* __restrict__ outO) {
  __shared__ float tile[32][33];
  const int m = blockIdx.z;
  const float* w = (m == 0) ? w0 : (m == 1) ? w1 : (m == 2) ? w2 : w3;
  u16* out = (m < 3) ? (outQKV + (size_t)m * CDIM * CDIM) : outO;
  const int n0 = blockIdx.x * 32;
  const int k0 = blockIdx.y * 32;
  const int tx = threadIdx.x, ty = threadIdx.y;  // block (32, 8)
#pragma unroll
  for (int i = 0; i < 4; ++i)
    tile[ty + i * 8][tx] = w[(size_t)(k0 + ty + i * 8) * CDIM + n0 + tx];
  __syncthreads();
#pragma unroll
  for (int i = 0; i < 4; ++i)
    out[(size_t)(n0 + ty + i * 8) * CDIM + k0 + tx] = f2bf(tile[tx][ty + i * 8]);
}

__global__ __launch_bounds__(256) void bias_concat_kernel(const float* __restrict__ bq,
                                                          const float* __restrict__ bk,
                                                          const float* __restrict__ bv,
                                                          float* __restrict__ out) {
  int i = blockIdx.x * 256 + threadIdx.x;  // 0..3071
  if (i < 3 * CDIM) {
    float v = (i < CDIM) ? bq[i] : (i < 2 * CDIM) ? bk[i - CDIM] : bv[i - 2 * CDIM];
    out[i] = v;
  }
}

// ---------------- GEMM: C[M][N] = A[M][K] @ Bt[N][K]^T + bias ----------------
// 128x128 tile, BK=32, 256 threads = 4 waves (2x2), wave tile 64x64 (4x4 16x16 frags)

template <typename OutT>
__global__ __launch_bounds__(256) void gemm_bt_kernel(
    const u16* __restrict__ A, const u16* __restrict__ Bt,
    const float* __restrict__ bias, OutT* __restrict__ C, int M, int N, int K) {
  __shared__ u16 As[128 * 32];
  __shared__ u16 Bs[128 * 32];
  const int t = threadIdx.x;
  const int lane = t & 63;
  const int w = t >> 6;
  const int wr = w >> 1, wc = w & 1;
  const int m0 = blockIdx.x * 128;
  const int n0 = blockIdx.y * 128;
  const int l15 = lane & 15;
  const int lg = lane >> 4;

  f32x4 acc[4][4];
#pragma unroll
  for (int i = 0; i < 4; ++i)
#pragma unroll
    for (int j = 0; j < 4; ++j) acc[i][j] = f32x4{0.f, 0.f, 0.f, 0.f};

  for (int k0 = 0; k0 < K; k0 += 32) {
    __syncthreads();
#pragma unroll
    for (int p = 0; p < 2; ++p) {
      int off = (p * 256 + t) * 8;  // ushort offset into 128x32 tile
      int row = off >> 5;
      int col = off & 31;
      *(u16x8*)(&As[off]) = *(const u16x8*)(&A[(size_t)(m0 + row) * K + k0 + col]);
      *(u16x8*)(&Bs[off]) = *(const u16x8*)(&Bt[(size_t)(n0 + row) * K + k0 + col]);
    }
    __syncthreads();
    u16x8 af[4], bf[4];
#pragma unroll
    for (int i = 0; i < 4; ++i)
      af[i] = *(const u16x8*)(&As[(wr * 64 + i * 16 + l15) * 32 + lg * 8]);
#pragma unroll
    for (int j = 0; j < 4; ++j)
      bf[j] = *(const u16x8*)(&Bs[(wc * 64 + j * 16 + l15) * 32 + lg * 8]);
#pragma unroll
    for (int i = 0; i < 4; ++i)
#pragma unroll
      for (int j = 0; j < 4; ++j) acc[i][j] = mfma_bf16(af[i], bf[j], acc[i][j]);
  }

#pragma unroll
  for (int j = 0; j < 4; ++j) {
    int col = n0 + wc * 64 + j * 16 + l15;
    float bv = bias[col];
#pragma unroll
    for (int i = 0; i < 4; ++i) {
#pragma unroll
      for (int r = 0; r < 4; ++r) {
        int row = m0 + wr * 64 + i * 16 + lg * 4 + r;
        float val = acc[i][j][r] + bv;
        if constexpr (std::is_same<OutT, float>::value)
          C[(size_t)row * N + col] = val;
        else
          C[(size_t)row * N + col] = f2bf(val);
      }
    }
  }
}

// ---------------- causal flash attention ----------------
// block = (qtile, head, batch); 256 threads = 4 waves, wave owns 16 q-rows.
// K/V tiles of 64 staged in LDS (V transposed), online softmax in registers.

__global__ __launch_bounds__(256) void attn_kernel(const u16* __restrict__ QKV,
                                                   u16* __restrict__ O) {
  constexpr int LDK = 72;  // padded row stride (ushorts): 144B -> 2-way banks (free)
  __shared__ u16 Ks[64 * LDK];
  __shared__ u16 Vt[64 * LDK];
  __shared__ u16 Ps[4 * 16 * LDK];

  const int t = threadIdx.x;
  const int lane = t & 63;
  const int w = t >> 6;
  const int l15 = lane & 15, lg = lane >> 4;
  const int qt = blockIdx.x;  // 0..31
  const int h = blockIdx.y;
  const int b = blockIdx.z;
  const int q0 = qt * 64;
  const int qrowbase = q0 + w * 16;

  const size_t RS = 3 * CDIM;  // QKV row stride
  const u16* Qp = QKV + (size_t)(b * TSEQ) * RS + h * DHEAD;
  const u16* Kp = Qp + CDIM;
  const u16* Vp = Qp + 2 * CDIM;

  u16x8 qf[2];
#pragma unroll
  for (int c = 0; c < 2; ++c)
    qf[c] = *(const u16x8*)(&Qp[(size_t)(qrowbase + l15) * RS + c * 32 + lg * 8]);

  f32x4 acc[4];
#pragma unroll
  for (int g = 0; g < 4; ++g) acc[g] = f32x4{0.f, 0.f, 0.f, 0.f};
  float mrow[4], lrow[4];
#pragma unroll
  for (int r = 0; r < 4; ++r) { mrow[r] = -1e30f; lrow[r] = 0.f; }

  const int nkb = qt + 1;
  for (int kb = 0; kb < nkb; ++kb) {
    __syncthreads();  // protect Ks/Vt from previous iteration's readers
#pragma unroll
    for (int p = 0; p < 2; ++p) {
      int c = p * 256 + t;      // 0..511 chunks of 8 ushorts (64 rows x 8 chunks)
      int row = c >> 3;
      int cc = (c & 7) * 8;
      *(u16x8*)(&Ks[row * LDK + cc]) =
          *(const u16x8*)(&Kp[(size_t)(kb * 64 + row) * RS + cc]);
      u16x8 v = *(const u16x8*)(&Vp[(size_t)(kb * 64 + row) * RS + cc]);
#pragma unroll
      for (int e = 0; e < 8; ++e) Vt[(cc + e) * LDK + row] = v[e];
    }
    __syncthreads();

    // S = Q K^T  (per wave: 16 q-rows x 64 k-cols)
    f32x4 sfr[4];
#pragma unroll
    for (int f = 0; f < 4; ++f) {
      f32x4 s = f32x4{0.f, 0.f, 0.f, 0.f};
#pragma unroll
      for (int c = 0; c < 2; ++c) {
        u16x8 kf = *(const u16x8*)(&Ks[(f * 16 + l15) * LDK + c * 32 + lg * 8]);
        s = mfma_bf16(qf[c], kf, s);
      }
      sfr[f] = s;
    }

    const bool diag = (kb == qt);
#pragma unroll
    for (int f = 0; f < 4; ++f)
#pragma unroll
      for (int r = 0; r < 4; ++r) {
        float sv = sfr[f][r] * 0.125f;  // 1/sqrt(64)
        if (diag) {
          int qrow = qrowbase + lg * 4 + r;
          int kcol = kb * 64 + f * 16 + l15;
          if (kcol > qrow) sv = -1e9f;
        }
        sfr[f][r] = sv;
      }

    // online softmax (rows live in 16-lane groups; reduce via shfl_xor 1,2,4,8)
#pragma unroll
    for (int r = 0; r < 4; ++r) {
      float mx = fmaxf(fmaxf(sfr[0][r], sfr[1][r]), fmaxf(sfr[2][r], sfr[3][r]));
#pragma unroll
      for (int msk = 1; msk < 16; msk <<= 1) mx = fmaxf(mx, __shfl_xor(mx, msk));
      float mnew = fmaxf(mrow[r], mx);
      float factor = __expf(mrow[r] - mnew);
      mrow[r] = mnew;
      lrow[r] *= factor;
#pragma unroll
      for (int g = 0; g < 4; ++g) acc[g][r] *= factor;
      float rs = 0.f;
#pragma unroll
      for (int f = 0; f < 4; ++f) {
        float p = __expf(sfr[f][r] - mnew);
        sfr[f][r] = p;
        rs += p;
      }
#pragma unroll
      for (int msk = 1; msk < 16; msk <<= 1) rs += __shfl_xor(rs, msk);
      lrow[r] += rs;
    }

    // P -> LDS (re-layout for PV A-operand); per-wave region, no barrier needed
#pragma unroll
    for (int f = 0; f < 4; ++f)
#pragma unroll
      for (int r = 0; r < 4; ++r)
        Ps[(w * 16 + lg * 4 + r) * LDK + f * 16 + l15] = f2bf(sfr[f][r]);

    // O += P @ V
#pragma unroll
    for (int c = 0; c < 2; ++c) {
      u16x8 pf = *(const u16x8*)(&Ps[(w * 16 + l15) * LDK + c * 32 + lg * 8]);
#pragma unroll
      for (int g = 0; g < 4; ++g) {
        u16x8 vf = *(const u16x8*)(&Vt[(g * 16 + l15) * LDK + c * 32 + lg * 8]);
        acc[g] = mfma_bf16(pf, vf, acc[g]);
      }
    }
  }

#pragma unroll
  for (int g = 0; g < 4; ++g)
#pragma unroll
    for (int r = 0; r < 4; ++r) {
      float val = acc[g][r] / lrow[r];
      O[(size_t)(b * TSEQ + q0 + w * 16 + lg * 4 + r) * CDIM + h * DHEAD + g * 16 + l15] =
          f2bf(val);
    }
}

// ---------------- launch ----------------

extern "C" void kernel_launch(void* const* d_in, const int* in_sizes, int n_in,
                              void* d_out, int out_size, void* d_ws, size_t ws_size,
                              hipStream_t stream) {
  const float* x  = (const float*)d_in[0];
  const float* wq = (const float*)d_in[1];
  const float* bq = (const float*)d_in[2];
  const float* wk = (const float*)d_in[3];
  const float* bk = (const float*)d_in[4];
  const float* wv = (const float*)d_in[5];
  const float* bv = (const float*)d_in[6];
  const float* wo = (const float*)d_in[7];
  const float* bo = (const float*)d_in[8];
  float* out = (float*)d_out;

  char* ws = (char*)d_ws;
  u16*  xb      = (u16*)(ws);
  u16*  wqkvT   = (u16*)(ws + (8ll << 20));
  u16*  woT     = (u16*)(ws + (14ll << 20));
  u16*  QKV     = (u16*)(ws + (16ll << 20));
  u16*  Obuf    = (u16*)(ws + (40ll << 20));
  float* biasqkv = (float*)(ws + (48ll << 20));

  cast_x_kernel<<<(NROWS * CDIM / 4 + 255) / 256, 256, 0, stream>>>(x, xb, NROWS * CDIM / 4);
  {
    dim3 g(CDIM / 32, CDIM / 32, 4), blk(32, 8);
    transpose_cast_kernel<<<g, blk, 0, stream>>>(wq, wk, wv, wo, wqkvT, woT);
  }
  bias_concat_kernel<<<12, 256, 0, stream>>>(bq, bk, bv, biasqkv);
  {
    dim3 g(NROWS / 128, (3 * CDIM) / 128);
    gemm_bt_kernel<u16><<<g, 256, 0, stream>>>(xb, wqkvT, biasqkv, QKV, NROWS, 3 * CDIM, CDIM);
  }
  {
    dim3 g(TSEQ / 64, NHEAD, BATCH);
    attn_kernel<<<g, 256, 0, stream>>>(QKV, Obuf);
  }
  {
    dim3 g(NROWS / 128, CDIM / 128);
    gemm_bt_kernel<float><<<g, 256, 0, stream>>>(Obuf, woT, bo, out, NROWS, CDIM, CDIM);
  }
}

// Round 2
// 173.531 us; speedup vs baseline: 1.4013x; 1.4013x over previous
//
#include <hip/hip_runtime.h>
#include <cstdint>
#include <type_traits>

// GPT MHA forward. B=2, T=2048, C=1024, H=16, d=64.
// Pipeline: cast x -> bf16 | transpose weights | bias concat | QKV GEMM (gload_lds)
//           | V-transpose kernel | causal flash attn (swapped QK^T, O^T epilogue)
//           | out-proj GEMM.
// Workspace: xb@0 (8MB, later aliased by Vt), wqkvT@8M, woT@14M, QKV@16M,
//            Obuf@40M, biasqkv@48M.

#define TSEQ  2048
#define BATCH 2
#define CDIM  1024
#define NHEAD 16
#define DHEAD 64
#define NROWS (BATCH * TSEQ)  // 4096

typedef unsigned short u16;
typedef u16   u16x8  __attribute__((ext_vector_type(8)));
typedef __bf16 bf16x8 __attribute__((ext_vector_type(8)));
typedef float f32x4  __attribute__((ext_vector_type(4)));

typedef const __attribute__((address_space(1))) void* gas_vp;
typedef __attribute__((address_space(3))) void* las_vp;

__device__ __forceinline__ u16 f2bf(float f) {
  union { float f; uint32_t u; } v; v.f = f;
  uint32_t u = v.u;
  return (u16)((u + 0x7FFFu + ((u >> 16) & 1u)) >> 16);  // RNE
}

__device__ __forceinline__ uint32_t pack2bf(float a, float b) {
  return (uint32_t)f2bf(a) | ((uint32_t)f2bf(b) << 16);
}

__device__ __forceinline__ f32x4 mfma_bf16(u16x8 a, u16x8 b, f32x4 c) {
  return __builtin_amdgcn_mfma_f32_16x16x32_bf16(
      __builtin_bit_cast(bf16x8, a), __builtin_bit_cast(bf16x8, b), c, 0, 0, 0);
}

// async global(16B/lane) -> LDS(wave-uniform base + lane*16)
__device__ __forceinline__ void gload16(const u16* g, u16* l) {
  __builtin_amdgcn_global_load_lds((gas_vp)g, (las_vp)l, 16, 0, 0);
}

// ---------------- prep kernels ----------------

__global__ __launch_bounds__(256) void cast_x_kernel(const float* __restrict__ in,
                                                     u16* __restrict__ out, int n4) {
  int i = blockIdx.x * 256 + threadIdx.x;
  if (i < n4) {
    float4 v = ((const float4*)in)[i];
    uint32_t lo = pack2bf(v.x, v.y);
    uint32_t hi = pack2bf(v.z, v.w);
    ((uint2*)out)[i] = make_uint2(lo, hi);
  }
}

__global__ __launch_bounds__(256) void transpose_cast_kernel(
    const float* __restrict__ w0, const float* __restrict__ w1,
    const float* __restrict__ w2, const float* __restrict__ w3,
    u16* __restrict__ outQKV, u16* __restrict__ outO) {
  __shared__ float tile[32][33];
  const int m = blockIdx.z;
  const float* w = (m == 0) ? w0 : (m == 1) ? w1 : (m == 2) ? w2 : w3;
  u16* out = (m < 3) ? (outQKV + (size_t)m * CDIM * CDIM) : outO;
  const int n0 = blockIdx.x * 32;
  const int k0 = blockIdx.y * 32;
  const int tx = threadIdx.x, ty = threadIdx.y;  // block (32, 8)
#pragma unroll
  for (int i = 0; i < 4; ++i)
    tile[ty + i * 8][tx] = w[(size_t)(k0 + ty + i * 8) * CDIM + n0 + tx];
  __syncthreads();
#pragma unroll
  for (int i = 0; i < 4; ++i)
    out[(size_t)(n0 + ty + i * 8) * CDIM + k0 + tx] = f2bf(tile[tx][ty + i * 8]);
}

__global__ __launch_bounds__(256) void bias_concat_kernel(const float* __restrict__ bq,
                                                          const float* __restrict__ bk,
                                                          const float* __restrict__ bv,
                                                          float* __restrict__ out) {
  int i = blockIdx.x * 256 + threadIdx.x;
  if (i < 3 * CDIM) {
    float v = (i < CDIM) ? bq[i] : (i < 2 * CDIM) ? bk[i - CDIM] : bv[i - 2 * CDIM];
    out[i] = v;
  }
}

// V part of QKV [B*T][3C] -> Vt [B][H][D][T]
__global__ __launch_bounds__(256) void vtrans_kernel(const u16* __restrict__ QKV,
                                                     u16* __restrict__ Vt) {
  __shared__ u16 tile[32][33];
  const int bh = blockIdx.z;
  const int b = bh >> 4, h = bh & 15;
  const int t0 = blockIdx.x * 32, d0 = blockIdx.y * 32;
  const int tx = threadIdx.x, ty = threadIdx.y;  // block (32, 8)
#pragma unroll
  for (int i = 0; i < 4; ++i)
    tile[ty + i * 8][tx] =
        QKV[(size_t)(b * TSEQ + t0 + ty + i * 8) * (3 * CDIM) + 2 * CDIM + h * DHEAD + d0 + tx];
  __syncthreads();
#pragma unroll
  for (int i = 0; i < 4; ++i)
    Vt[(size_t)((b * NHEAD + h) * DHEAD + d0 + ty + i * 8) * TSEQ + t0 + tx] =
        tile[tx][ty + i * 8];
}

// ---------------- GEMM: C[M][N] = A[M][K] @ Bt[N][K]^T + bias ----------------
// 128x128 tile, BK=32, 4 waves, global_load_lds width-16 staging (m97 structure)

template <typename OutT>
__global__ __launch_bounds__(256) void gemm_bt_kernel(
    const u16* __restrict__ A, const u16* __restrict__ Bt,
    const float* __restrict__ bias, OutT* __restrict__ C, int M, int N, int K) {
  __shared__ u16 As[128 * 32];
  __shared__ u16 Bs[128 * 32];
  const int t = threadIdx.x;
  const int lane = t & 63;
  const int w = t >> 6;
  const int wr = w >> 1, wc = w & 1;
  const int m0 = blockIdx.x * 128;
  const int n0 = blockIdx.y * 128;
  const int l15 = lane & 15;
  const int lg = lane >> 4;
  const int srow = lane >> 2;         // 0..15
  const int scol = (lane & 3) * 8;    // u16 col in BK=32

  f32x4 acc[4][4];
#pragma unroll
  for (int i = 0; i < 4; ++i)
#pragma unroll
    for (int j = 0; j < 4; ++j) acc[i][j] = f32x4{0.f, 0.f, 0.f, 0.f};

  for (int k0 = 0; k0 < K; k0 += 32) {
    __syncthreads();
#pragma unroll
    for (int ci = 0; ci < 2; ++ci) {
      const int chunk = w * 2 + ci;           // 0..7 (wave-uniform)
      const int grow = chunk * 16 + srow;
      gload16(&A[(size_t)(m0 + grow) * K + k0 + scol], &As[chunk * 512]);
      gload16(&Bt[(size_t)(n0 + grow) * K + k0 + scol], &Bs[chunk * 512]);
    }
    __syncthreads();  // compiler drains vmcnt before s_barrier
    u16x8 af[4], bf[4];
#pragma unroll
    for (int i = 0; i < 4; ++i)
      af[i] = *(const u16x8*)(&As[(wr * 64 + i * 16 + l15) * 32 + lg * 8]);
#pragma unroll
    for (int j = 0; j < 4; ++j)
      bf[j] = *(const u16x8*)(&Bs[(wc * 64 + j * 16 + l15) * 32 + lg * 8]);
#pragma unroll
    for (int i = 0; i < 4; ++i)
#pragma unroll
      for (int j = 0; j < 4; ++j) acc[i][j] = mfma_bf16(af[i], bf[j], acc[i][j]);
  }

#pragma unroll
  for (int j = 0; j < 4; ++j) {
    int col = n0 + wc * 64 + j * 16 + l15;
    float bv = bias[col];
#pragma unroll
    for (int i = 0; i < 4; ++i) {
#pragma unroll
      for (int r = 0; r < 4; ++r) {
        int row = m0 + wr * 64 + i * 16 + lg * 4 + r;
        float val = acc[i][j][r] + bv;
        if constexpr (std::is_same<OutT, float>::value)
          C[(size_t)row * N + col] = val;
        else
          C[(size_t)row * N + col] = f2bf(val);
      }
    }
  }
}

// ---------------- causal flash attention (swapped operands) ----------------
// block = (qtile reversed, head, batch); 4 waves x 16 q-rows; KVBLK=64.
// QK^T computed as mfma(K,Q) -> lane holds S^T[k][q=lane&15]: softmax is
// in-lane (16 vals) + 2 shfl_xor. PV computed as mfma(V^T,P) -> O^T in acc,
// un-transposed via per-wave LDS in the epilogue.

__global__ __launch_bounds__(256) void attn_kernel(const u16* __restrict__ QKV,
                                                   const u16* __restrict__ Vt,
                                                   u16* __restrict__ O) {
  constexpr int LDK = 72;  // padded row stride (u16): 2-way banks = free
  __shared__ u16 Ks[64 * LDK];
  __shared__ u16 Vs[64 * LDK];  // V^T tile: [n=64][k=64]
  __shared__ u16 Ps[64 * LDK];  // P[q][k]; reused as O[q][n] in epilogue

  const int t = threadIdx.x;
  const int lane = t & 63;
  const int wq = t >> 6;
  const int l15 = lane & 15, lg = lane >> 4;
  const int qt = 31 - blockIdx.x;  // heavy q-tiles dispatch first
  const int h = blockIdx.y, b = blockIdx.z;
  const int q0 = qt * 64;
  const int qrow = q0 + wq * 16;

  const size_t RS = 3 * CDIM;
  const u16* Qp = QKV + (size_t)(b * TSEQ) * RS + h * DHEAD;
  const u16* Kp = Qp + CDIM;
  const u16* Vgp = Vt + (size_t)(b * NHEAD + h) * DHEAD * TSEQ;

  // Q fragment (B-operand: row q = l15, k elems lg*8 + 0..7)
  u16x8 qf[2];
#pragma unroll
  for (int c = 0; c < 2; ++c)
    qf[c] = *(const u16x8*)(&Qp[(size_t)(qrow + l15) * RS + c * 32 + lg * 8]);

  f32x4 acc[4];
#pragma unroll
  for (int g = 0; g < 4; ++g) acc[g] = f32x4{0.f, 0.f, 0.f, 0.f};
  float m_run = -3e38f, l_run = 0.f;

  const int srow = t >> 3;        // 0..31
  const int scc = (t & 7) * 8;    // 0..56

  for (int kb = 0; kb <= qt; ++kb) {
    __syncthreads();
#pragma unroll
    for (int p = 0; p < 2; ++p) {
      int row = p * 32 + srow;
      *(u16x8*)(&Ks[row * LDK + scc]) =
          *(const u16x8*)(&Kp[(size_t)(kb * 64 + row) * RS + scc]);
      *(u16x8*)(&Vs[row * LDK + scc]) =
          *(const u16x8*)(&Vgp[(size_t)row * TSEQ + kb * 64 + scc]);
    }
    __syncthreads();

    // S^T[k][q]: per f-frag rows k = f*16 + lg*4 + r, col q = l15
    f32x4 sfr[4];
#pragma unroll
    for (int f = 0; f < 4; ++f) {
      f32x4 s = f32x4{0.f, 0.f, 0.f, 0.f};
#pragma unroll
      for (int c = 0; c < 2; ++c) {
        u16x8 kf = *(const u16x8*)(&Ks[(f * 16 + l15) * LDK + c * 32 + lg * 8]);
        s = mfma_bf16(kf, qf[c], s);
      }
      sfr[f] = s;
    }

    const bool diag = (kb == qt);
    const int q_abs = qrow + l15;
#pragma unroll
    for (int f = 0; f < 4; ++f)
#pragma unroll
      for (int r = 0; r < 4; ++r) {
        float sv = sfr[f][r] * 0.125f;  // 1/sqrt(64)
        if (diag) {
          int k_abs = kb * 64 + f * 16 + lg * 4 + r;
          if (k_abs > q_abs) sv = -1e9f;
        }
        sfr[f][r] = sv;
      }

    // row-max: in-lane over 16, then combine 4 lanes holding same q
    float mx = sfr[0][0];
#pragma unroll
    for (int f = 0; f < 4; ++f)
#pragma unroll
      for (int r = 0; r < 4; ++r) mx = fmaxf(mx, sfr[f][r]);
    mx = fmaxf(mx, __shfl_xor(mx, 16));
    mx = fmaxf(mx, __shfl_xor(mx, 32));

    float mnew = fmaxf(m_run, mx);
    float fac = __expf(m_run - mnew);
    m_run = mnew;
    l_run *= fac;
#pragma unroll
    for (int g = 0; g < 4; ++g) acc[g] *= fac;

    float ps = 0.f;
#pragma unroll
    for (int f = 0; f < 4; ++f)
#pragma unroll
      for (int r = 0; r < 4; ++r) {
        float p = __expf(sfr[f][r] - mnew);
        sfr[f][r] = p;
        ps += p;
      }
    ps += __shfl_xor(ps, 16);
    ps += __shfl_xor(ps, 32);
    l_run += ps;

    // P -> Ps[q][k] as packed u32 pairs (per-wave region, in-wave ordering)
#pragma unroll
    for (int f = 0; f < 4; ++f) {
      uint32_t lo = pack2bf(sfr[f][0], sfr[f][1]);
      uint32_t hi = pack2bf(sfr[f][2], sfr[f][3]);
      int base = (wq * 16 + l15) * LDK + f * 16 + lg * 4;
      *(uint32_t*)(&Ps[base]) = lo;
      *(uint32_t*)(&Ps[base + 2]) = hi;
    }

    // O^T += mfma(V^T rows n, P rows q): acc[g] rows n = g*16+lg*4+r, col q=l15
#pragma unroll
    for (int c = 0; c < 2; ++c) {
      u16x8 pf = *(const u16x8*)(&Ps[(wq * 16 + l15) * LDK + c * 32 + lg * 8]);
#pragma unroll
      for (int g = 0; g < 4; ++g) {
        u16x8 vf = *(const u16x8*)(&Vs[(g * 16 + l15) * LDK + c * 32 + lg * 8]);
        acc[g] = mfma_bf16(vf, pf, acc[g]);
      }
    }
  }

  // epilogue: normalize, un-transpose O^T via per-wave LDS, vector-store
  float inv = 1.f / l_run;
#pragma unroll
  for (int g = 0; g < 4; ++g)
#pragma unroll
    for (int r = 0; r < 4; ++r) {
      int n = g * 16 + lg * 4 + r;
      Ps[(wq * 16 + l15) * LDK + n] = f2bf(acc[g][r] * inv);
    }
#pragma unroll
  for (int i = 0; i < 2; ++i) {
    int rl = i * 8 + (lane >> 3);   // 0..15 local q row
    int cc = (lane & 7) * 8;
    u16x8 vv = *(const u16x8*)(&Ps[(wq * 16 + rl) * LDK + cc]);
    *(u16x8*)(&O[(size_t)(b * TSEQ + q0 + wq * 16 + rl) * CDIM + h * DHEAD + cc]) = vv;
  }
}

// ---------------- launch ----------------

extern "C" void kernel_launch(void* const* d_in, const int* in_sizes, int n_in,
                              void* d_out, int out_size, void* d_ws, size_t ws_size,
                              hipStream_t stream) {
  const float* x  = (const float*)d_in[0];
  const float* wq = (const float*)d_in[1];
  const float* bq = (const float*)d_in[2];
  const float* wk = (const float*)d_in[3];
  const float* bk = (const float*)d_in[4];
  const float* wv = (const float*)d_in[5];
  const float* bv = (const float*)d_in[6];
  const float* wo = (const float*)d_in[7];
  const float* bo = (const float*)d_in[8];
  float* out = (float*)d_out;

  char* ws = (char*)d_ws;
  u16*  xb      = (u16*)(ws);                 // 8MB; dead after QKV GEMM
  u16*  Vtg     = (u16*)(ws);                 // 8MB; aliases xb (written after)
  u16*  wqkvT   = (u16*)(ws + (8ll << 20));
  u16*  woT     = (u16*)(ws + (14ll << 20));
  u16*  QKV     = (u16*)(ws + (16ll << 20));
  u16*  Obuf    = (u16*)(ws + (40ll << 20));
  float* biasqkv = (float*)(ws + (48ll << 20));

  cast_x_kernel<<<(NROWS * CDIM / 4 + 255) / 256, 256, 0, stream>>>(x, xb, NROWS * CDIM / 4);
  {
    dim3 g(CDIM / 32, CDIM / 32, 4), blk(32, 8);
    transpose_cast_kernel<<<g, blk, 0, stream>>>(wq, wk, wv, wo, wqkvT, woT);
  }
  bias_concat_kernel<<<12, 256, 0, stream>>>(bq, bk, bv, biasqkv);
  {
    dim3 g(NROWS / 128, (3 * CDIM) / 128);
    gemm_bt_kernel<u16><<<g, 256, 0, stream>>>(xb, wqkvT, biasqkv, QKV, NROWS, 3 * CDIM, CDIM);
  }
  {
    dim3 g(TSEQ / 32, DHEAD / 32, BATCH * NHEAD), blk(32, 8);
    vtrans_kernel<<<g, blk, 0, stream>>>(QKV, Vtg);
  }
  {
    dim3 g(TSEQ / 64, NHEAD, BATCH);
    attn_kernel<<<g, 256, 0, stream>>>(QKV, Vtg, Obuf);
  }
  {
    dim3 g(NROWS / 128, CDIM / 128);
    gemm_bt_kernel<float><<<g, 256, 0, stream>>>(Obuf, woT, bo, out, NROWS, CDIM, CDIM);
  }
}

// Round 3
// 163.114 us; speedup vs baseline: 1.4908x; 1.0639x over previous
//
#include <hip/hip_runtime.h>
#include <cstdint>
#include <type_traits>

// GPT MHA forward. B=2, T=2048, C=1024, H=16, d=64.
// cast x->bf16 | transpose weights (wq pre-scaled by 0.125*log2e) | bias concat
// | QKV GEMM (gload_lds, XCD swizzle) | V-transpose | causal flash attn
//   (swapped QK^T, exp2 softmax, defer-max, async-STAGE) | out-proj GEMM.

#define TSEQ  2048
#define BATCH 2
#define CDIM  1024
#define NHEAD 16
#define DHEAD 64
#define NROWS (BATCH * TSEQ)  // 4096

// 0.125 (1/sqrt(d)) * log2(e): folded into wq/bq so softmax uses exp2
#define QSCALE 0.1803368801111244f

typedef unsigned short u16;
typedef u16   u16x8  __attribute__((ext_vector_type(8)));
typedef __bf16 bf16x8 __attribute__((ext_vector_type(8)));
typedef __bf16 bf16x2 __attribute__((ext_vector_type(2)));
typedef float f32x4  __attribute__((ext_vector_type(4)));

typedef const __attribute__((address_space(1))) void* gas_vp;
typedef __attribute__((address_space(3))) void* las_vp;

__device__ __forceinline__ u16 f2bf(float f) {  // native cast -> v_cvt_pk_bf16_f32
  return __builtin_bit_cast(u16, (__bf16)f);
}

__device__ __forceinline__ uint32_t pack2bf(float a, float b) {
  bf16x2 v;
  v[0] = (__bf16)a;
  v[1] = (__bf16)b;
  return __builtin_bit_cast(uint32_t, v);
}

__device__ __forceinline__ f32x4 mfma_bf16(u16x8 a, u16x8 b, f32x4 c) {
  return __builtin_amdgcn_mfma_f32_16x16x32_bf16(
      __builtin_bit_cast(bf16x8, a), __builtin_bit_cast(bf16x8, b), c, 0, 0, 0);
}

__device__ __forceinline__ void gload16(const u16* g, u16* l) {
  __builtin_amdgcn_global_load_lds((gas_vp)g, (las_vp)l, 16, 0, 0);
}

// ---------------- prep kernels ----------------

__global__ __launch_bounds__(256) void cast_x_kernel(const float* __restrict__ in,
                                                     u16* __restrict__ out, int n4) {
  int i = blockIdx.x * 256 + threadIdx.x;
  if (i < n4) {
    float4 v = ((const float4*)in)[i];
    ((uint2*)out)[i] = make_uint2(pack2bf(v.x, v.y), pack2bf(v.z, v.w));
  }
}

__global__ __launch_bounds__(256) void transpose_cast_kernel(
    const float* __restrict__ w0, const float* __restrict__ w1,
    const float* __restrict__ w2, const float* __restrict__ w3,
    u16* __restrict__ outQKV, u16* __restrict__ outO) {
  __shared__ float tile[32][33];
  const int m = blockIdx.z;
  const float* w = (m == 0) ? w0 : (m == 1) ? w1 : (m == 2) ? w2 : w3;
  const float scale = (m == 0) ? QSCALE : 1.0f;
  u16* out = (m < 3) ? (outQKV + (size_t)m * CDIM * CDIM) : outO;
  const int n0 = blockIdx.x * 32;
  const int k0 = blockIdx.y * 32;
  const int tx = threadIdx.x, ty = threadIdx.y;  // block (32, 8)
#pragma unroll
  for (int i = 0; i < 4; ++i)
    tile[ty + i * 8][tx] = w[(size_t)(k0 + ty + i * 8) * CDIM + n0 + tx];
  __syncthreads();
#pragma unroll
  for (int i = 0; i < 4; ++i)
    out[(size_t)(n0 + ty + i * 8) * CDIM + k0 + tx] = f2bf(tile[tx][ty + i * 8] * scale);
}

__global__ __launch_bounds__(256) void bias_concat_kernel(const float* __restrict__ bq,
                                                          const float* __restrict__ bk,
                                                          const float* __restrict__ bv,
                                                          float* __restrict__ out) {
  int i = blockIdx.x * 256 + threadIdx.x;
  if (i < 3 * CDIM) {
    float v = (i < CDIM) ? bq[i] * QSCALE
            : (i < 2 * CDIM) ? bk[i - CDIM] : bv[i - 2 * CDIM];
    out[i] = v;
  }
}

// V part of QKV [B*T][3C] -> Vt [B][H][D][T]
__global__ __launch_bounds__(256) void vtrans_kernel(const u16* __restrict__ QKV,
                                                     u16* __restrict__ Vt) {
  __shared__ u16 tile[32][33];
  const int bh = blockIdx.z;
  const int b = bh >> 4, h = bh & 15;
  const int t0 = blockIdx.x * 32, d0 = blockIdx.y * 32;
  const int tx = threadIdx.x, ty = threadIdx.y;  // block (32, 8)
#pragma unroll
  for (int i = 0; i < 4; ++i)
    tile[ty + i * 8][tx] =
        QKV[(size_t)(b * TSEQ + t0 + ty + i * 8) * (3 * CDIM) + 2 * CDIM + h * DHEAD + d0 + tx];
  __syncthreads();
#pragma unroll
  for (int i = 0; i < 4; ++i)
    Vt[(size_t)((b * NHEAD + h) * DHEAD + d0 + ty + i * 8) * TSEQ + t0 + tx] =
        tile[tx][ty + i * 8];
}

// ---------------- GEMM: C[M][N] = A[M][K] @ Bt[N][K]^T + bias ----------------
// 128x128 tile, BK=32, 4 waves, global_load_lds staging; 1D grid + XCD swizzle.

template <typename OutT>
__global__ __launch_bounds__(256) void gemm_bt_kernel(
    const u16* __restrict__ A, const u16* __restrict__ Bt,
    const float* __restrict__ bias, OutT* __restrict__ C,
    int M, int N, int K, int mblocks) {
  __shared__ u16 As[128 * 32];
  __shared__ u16 Bs[128 * 32];
  // XCD-aware bijective remap (nwg % 8 == 0 for all our launches)
  const int nwg = gridDim.x;
  const int lid = blockIdx.x;
  const int swz = (lid & 7) * (nwg >> 3) + (lid >> 3);
  const int m0 = (swz % mblocks) * 128;
  const int n0 = (swz / mblocks) * 128;

  const int t = threadIdx.x;
  const int lane = t & 63;
  const int w = t >> 6;
  const int wr = w >> 1, wc = w & 1;
  const int l15 = lane & 15;
  const int lg = lane >> 4;
  const int srow = lane >> 2;
  const int scol = (lane & 3) * 8;

  f32x4 acc[4][4];
#pragma unroll
  for (int i = 0; i < 4; ++i)
#pragma unroll
    for (int j = 0; j < 4; ++j) acc[i][j] = f32x4{0.f, 0.f, 0.f, 0.f};

  for (int k0 = 0; k0 < K; k0 += 32) {
    __syncthreads();
#pragma unroll
    for (int ci = 0; ci < 2; ++ci) {
      const int chunk = w * 2 + ci;
      const int grow = chunk * 16 + srow;
      gload16(&A[(size_t)(m0 + grow) * K + k0 + scol], &As[chunk * 512]);
      gload16(&Bt[(size_t)(n0 + grow) * K + k0 + scol], &Bs[chunk * 512]);
    }
    __syncthreads();
    u16x8 af[4], bf[4];
#pragma unroll
    for (int i = 0; i < 4; ++i)
      af[i] = *(const u16x8*)(&As[(wr * 64 + i * 16 + l15) * 32 + lg * 8]);
#pragma unroll
    for (int j = 0; j < 4; ++j)
      bf[j] = *(const u16x8*)(&Bs[(wc * 64 + j * 16 + l15) * 32 + lg * 8]);
#pragma unroll
    for (int i = 0; i < 4; ++i)
#pragma unroll
      for (int j = 0; j < 4; ++j) acc[i][j] = mfma_bf16(af[i], bf[j], acc[i][j]);
  }

#pragma unroll
  for (int j = 0; j < 4; ++j) {
    int col = n0 + wc * 64 + j * 16 + l15;
    float bv = bias[col];
#pragma unroll
    for (int i = 0; i < 4; ++i) {
#pragma unroll
      for (int r = 0; r < 4; ++r) {
        int row = m0 + wr * 64 + i * 16 + lg * 4 + r;
        float val = acc[i][j][r] + bv;
        if constexpr (std::is_same<OutT, float>::value)
          C[(size_t)row * N + col] = val;
        else
          C[(size_t)row * N + col] = f2bf(val);
      }
    }
  }
}

// ---------------- causal flash attention (swapped operands) ----------------
// mfma(K,Q) -> lane holds S^T[k][q=lane&15]; softmax in-lane + 2 shfl.
// T13 defer-max (THR=8, log2 domain); T14 async-STAGE (load regs early,
// ds_write after barrier). PV as mfma(V^T,P) -> O^T, un-transposed in epilogue.

__global__ __launch_bounds__(256) void attn_kernel(const u16* __restrict__ QKV,
                                                   const u16* __restrict__ Vt,
                                                   u16* __restrict__ O) {
  constexpr int LDK = 72;
  __shared__ u16 Ks[64 * LDK];
  __shared__ u16 Vs[64 * LDK];  // V^T tile: [d=64][k=64]
  __shared__ u16 Ps[64 * LDK];  // P[q][k]; reused as O[q][n] in epilogue

  const int t = threadIdx.x;
  const int lane = t & 63;
  const int wq = t >> 6;
  const int l15 = lane & 15, lg = lane >> 4;
  const int qt = 31 - blockIdx.x;  // heavy q-tiles first
  const int h = blockIdx.y, b = blockIdx.z;
  const int q0 = qt * 64;
  const int qrow = q0 + wq * 16;

  const size_t RS = 3 * CDIM;
  const u16* Qp = QKV + (size_t)(b * TSEQ) * RS + h * DHEAD;
  const u16* Kp = Qp + CDIM;
  const u16* Vgp = Vt + (size_t)(b * NHEAD + h) * DHEAD * TSEQ;

  u16x8 qf[2];
#pragma unroll
  for (int c = 0; c < 2; ++c)
    qf[c] = *(const u16x8*)(&Qp[(size_t)(qrow + l15) * RS + c * 32 + lg * 8]);

  f32x4 acc[4];
#pragma unroll
  for (int g = 0; g < 4; ++g) acc[g] = f32x4{0.f, 0.f, 0.f, 0.f};
  float m_run = -3e38f, l_run = 0.f;

  const int srow = t >> 3;
  const int scc = (t & 7) * 8;

  // T14 prologue: first K/V tile -> regs
  u16x8 kreg[2], vreg[2];
#pragma unroll
  for (int p = 0; p < 2; ++p) {
    int row = p * 32 + srow;
    kreg[p] = *(const u16x8*)(&Kp[(size_t)row * RS + scc]);
    vreg[p] = *(const u16x8*)(&Vgp[(size_t)row * TSEQ + scc]);
  }

  for (int kb = 0; kb <= qt; ++kb) {
    __syncthreads();  // all waves done reading previous tile
#pragma unroll
    for (int p = 0; p < 2; ++p) {
      int row = p * 32 + srow;
      *(u16x8*)(&Ks[row * LDK + scc]) = kreg[p];
      *(u16x8*)(&Vs[row * LDK + scc]) = vreg[p];
    }
    __syncthreads();

    // issue next-tile loads now; latency hides under compute below
    if (kb < qt) {
#pragma unroll
      for (int p = 0; p < 2; ++p) {
        int row = p * 32 + srow;
        kreg[p] = *(const u16x8*)(&Kp[(size_t)((kb + 1) * 64 + row) * RS + scc]);
        vreg[p] = *(const u16x8*)(&Vgp[(size_t)row * TSEQ + (kb + 1) * 64 + scc]);
      }
    }

    // S^T[k][q]: rows k = f*16 + lg*4 + r, col q = l15 (pre-scaled by QSCALE)
    f32x4 sfr[4];
#pragma unroll
    for (int f = 0; f < 4; ++f) {
      f32x4 s = f32x4{0.f, 0.f, 0.f, 0.f};
#pragma unroll
      for (int c = 0; c < 2; ++c) {
        u16x8 kf = *(const u16x8*)(&Ks[(f * 16 + l15) * LDK + c * 32 + lg * 8]);
        s = mfma_bf16(kf, qf[c], s);
      }
      sfr[f] = s;
    }

    if (kb == qt) {  // diagonal tile: causal mask
      const int q_abs = qrow + l15;
#pragma unroll
      for (int f = 0; f < 4; ++f)
#pragma unroll
        for (int r = 0; r < 4; ++r) {
          int k_abs = kb * 64 + f * 16 + lg * 4 + r;
          if (k_abs > q_abs) sfr[f][r] = -1e9f;
        }
    }

    // row-max: in-lane over 16, combine the 4 lane-groups sharing q
    float mx = sfr[0][0];
#pragma unroll
    for (int f = 0; f < 4; ++f)
#pragma unroll
      for (int r = 0; r < 4; ++r) mx = fmaxf(mx, sfr[f][r]);
    mx = fmaxf(mx, __shfl_xor(mx, 16));
    mx = fmaxf(mx, __shfl_xor(mx, 32));

    // T13: rescale only when the tile max meaningfully exceeds m_run
    if (__any(mx > m_run + 8.f)) {
      float mnew = fmaxf(m_run, mx);
      float fac = exp2f(m_run - mnew);
      m_run = mnew;
      l_run *= fac;
#pragma unroll
      for (int g = 0; g < 4; ++g) acc[g] *= fac;
    }

    float ps = 0.f;
#pragma unroll
    for (int f = 0; f < 4; ++f)
#pragma unroll
      for (int r = 0; r < 4; ++r) {
        float p = exp2f(sfr[f][r] - m_run);
        sfr[f][r] = p;
        ps += p;
      }
    ps += __shfl_xor(ps, 16);
    ps += __shfl_xor(ps, 32);
    l_run += ps;

    // P -> Ps[q][k] as packed u32 pairs (per-wave region; in-wave ordering)
#pragma unroll
    for (int f = 0; f < 4; ++f) {
      int base = (wq * 16 + l15) * LDK + f * 16 + lg * 4;
      *(uint32_t*)(&Ps[base]) = pack2bf(sfr[f][0], sfr[f][1]);
      *(uint32_t*)(&Ps[base + 2]) = pack2bf(sfr[f][2], sfr[f][3]);
    }

    // O^T += mfma(V^T, P)
#pragma unroll
    for (int c = 0; c < 2; ++c) {
      u16x8 pf = *(const u16x8*)(&Ps[(wq * 16 + l15) * LDK + c * 32 + lg * 8]);
#pragma unroll
      for (int g = 0; g < 4; ++g) {
        u16x8 vf = *(const u16x8*)(&Vs[(g * 16 + l15) * LDK + c * 32 + lg * 8]);
        acc[g] = mfma_bf16(vf, pf, acc[g]);
      }
    }
  }

  // epilogue: normalize, un-transpose via per-wave LDS region, vector-store
  float inv = 1.f / l_run;
#pragma unroll
  for (int g = 0; g < 4; ++g) {
    int base = (wq * 16 + l15) * LDK + g * 16 + lg * 4;
    *(uint32_t*)(&Ps[base]) = pack2bf(acc[g][0] * inv, acc[g][1] * inv);
    *(uint32_t*)(&Ps[base + 2]) = pack2bf(acc[g][2] * inv, acc[g][3] * inv);
  }
#pragma unroll
  for (int i = 0; i < 2; ++i) {
    int rl = i * 8 + (lane >> 3);
    int cc = (lane & 7) * 8;
    u16x8 vv = *(const u16x8*)(&Ps[(wq * 16 + rl) * LDK + cc]);
    *(u16x8*)(&O[(size_t)(b * TSEQ + q0 + wq * 16 + rl) * CDIM + h * DHEAD + cc]) = vv;
  }
}

// ---------------- launch ----------------

extern "C" void kernel_launch(void* const* d_in, const int* in_sizes, int n_in,
                              void* d_out, int out_size, void* d_ws, size_t ws_size,
                              hipStream_t stream) {
  const float* x  = (const float*)d_in[0];
  const float* wq = (const float*)d_in[1];
  const float* bq = (const float*)d_in[2];
  const float* wk = (const float*)d_in[3];
  const float* bk = (const float*)d_in[4];
  const float* wv = (const float*)d_in[5];
  const float* bv = (const float*)d_in[6];
  const float* wo = (const float*)d_in[7];
  const float* bo = (const float*)d_in[8];
  float* out = (float*)d_out;

  char* ws = (char*)d_ws;
  u16*  xb      = (u16*)(ws);                 // 8MB; dead after QKV GEMM
  u16*  Vtg     = (u16*)(ws);                 // aliases xb (written after)
  u16*  wqkvT   = (u16*)(ws + (8ll << 20));
  u16*  woT     = (u16*)(ws + (14ll << 20));
  u16*  QKV     = (u16*)(ws + (16ll << 20));
  u16*  Obuf    = (u16*)(ws + (40ll << 20));
  float* biasqkv = (float*)(ws + (48ll << 20));

  cast_x_kernel<<<(NROWS * CDIM / 4 + 255) / 256, 256, 0, stream>>>(x, xb, NROWS * CDIM / 4);
  {
    dim3 g(CDIM / 32, CDIM / 32, 4), blk(32, 8);
    transpose_cast_kernel<<<g, blk, 0, stream>>>(wq, wk, wv, wo, wqkvT, woT);
  }
  bias_concat_kernel<<<12, 256, 0, stream>>>(bq, bk, bv, biasqkv);
  gemm_bt_kernel<u16><<<(NROWS / 128) * ((3 * CDIM) / 128), 256, 0, stream>>>(
      xb, wqkvT, biasqkv, QKV, NROWS, 3 * CDIM, CDIM, NROWS / 128);
  {
    dim3 g(TSEQ / 32, DHEAD / 32, BATCH * NHEAD), blk(32, 8);
    vtrans_kernel<<<g, blk, 0, stream>>>(QKV, Vtg);
  }
  {
    dim3 g(TSEQ / 64, NHEAD, BATCH);
    attn_kernel<<<g, 256, 0, stream>>>(QKV, Vtg, Obuf);
  }
  gemm_bt_kernel<float><<<(NROWS / 128) * (CDIM / 128), 256, 0, stream>>>(
      Obuf, woT, bo, out, NROWS, CDIM, CDIM, NROWS / 128);
}